// Round 19
// baseline (94.783 us; speedup 1.0000x reference)
//
#include <hip/hip_runtime.h>
#include <cstdint>
#include <cstddef>

#define NN 1024
#define BB 4
#define CC 256
#define HH 4
#define DD 64
#define EE 32768
#define ROWS 8
#define CAP 128
#define NTHR 256

typedef float floatx4 __attribute__((ext_vector_type(4)));

struct Params {
    const float *x, *ef;
    const int *src, *trg;
    const float *Wn1, *We1, *as1, *at1, *ae1;
    const float *Wn2, *We2, *as2, *at2, *ae2;
    float *out;
    float *WnT1, *WnT2, *wsum, *pe, *hbuf, *alphas, *alphat;
    float *hbuf2, *alphas2, *alphat2;
    int *cnt, *bucket, *sedge_g, *ssrc_g;
};

// ---------------- proj: rows r0..r0+7 of (x @ Wn.T); x via wave-uniform scalar loads ----------------
__device__ __forceinline__ void proj_body(const float* __restrict__ x,
                                          const float* __restrict__ WT,
                                          const float* __restrict__ a_s,
                                          const float* __restrict__ a_t,
                                          float* __restrict__ hout,
                                          float* __restrict__ alpha_s,
                                          float* __restrict__ alpha_t,
                                          int bid, int t) {
    int r0 = bid * ROWS;
    const float* xr = x + (size_t)r0 * CC;
    float acc[ROWS];
#pragma unroll
    for (int j = 0; j < ROWS; ++j) acc[j] = 0.f;
#pragma unroll 4
    for (int c = 0; c < CC; ++c) {
        float w = WT[c * CC + t];
#pragma unroll
        for (int j = 0; j < ROWS; ++j) acc[j] += w * xr[(size_t)j * CC + c];
    }
    int h = t >> 6, d = t & 63;
    float as = a_s[h * DD + d], at = a_t[h * DD + d];
#pragma unroll
    for (int j = 0; j < ROWS; ++j) {
        hout[(size_t)(r0 + j) * CC + t] = acc[j];
        float vs = acc[j] * as, vt = acc[j] * at;
#pragma unroll
        for (int off = 32; off; off >>= 1) {
            vs += __shfl_down(vs, off, 64);
            vt += __shfl_down(vt, off, 64);
        }
        if (d == 0) {
            alpha_s[(size_t)(r0 + j) * HH + h] = vs;
            alpha_t[(size_t)(r0 + j) * HH + h] = vt;
        }
    }
}

// rank-sort node n's bucket (deg<=64 wave-parallel; else serial) into sed[]
__device__ __forceinline__ void sort_bucket(const Params& p, int n, int deg, int lane,
                                            int* sed) {
    if (deg <= 64) {
        int v = (lane < deg) ? p.bucket[n * CAP + lane] : 0x7fffffff;
        int rank = 0;
#pragma unroll
        for (int j = 0; j < 64; ++j) {
            int vj = __shfl(v, j, 64);
            rank += (vj < v) ? 1 : 0;
        }
        if (lane < deg) sed[rank] = v;
    } else if (lane == 0) {
        for (int i = 0; i < deg; ++i) sed[i] = p.bucket[n * CAP + i];
        for (int i = 1; i < deg; ++i) {
            int v = sed[i], j = i - 1;
            while (j >= 0 && sed[j] > v) { sed[j + 1] = sed[j]; --j; }
            sed[j + 1] = v;
        }
    }
}

// cooperative score+exp precompute: sex[i][b*4+h] for all deg*16 pairs
__device__ __forceinline__ void score_exp(const float* __restrict__ als,
                                          const float* salt, int t, int deg,
                                          const int* ssrc, const float (*spe)[HH],
                                          float (*sex)[16]) {
#pragma unroll
    for (int k = 0; k < 8; ++k) {
        int idx = k * NTHR + t;
        if (idx < deg * 16) {
            int i = idx >> 4, bh = idx & 15;
            int s = ssrc[i];
            float sc = als[(size_t)s * 16 + bh] + salt[bh] + spe[i][bh & 3];
            sc = sc > 0.f ? sc : 0.2f * sc;
            sex[i][bh] = __expf(sc);
        }
    }
}

// ---------------- K1: transposes + wsum + cnt zero ----------------
__global__ __launch_bounds__(NTHR) void k_prep(Params p) {
    __shared__ float tile[64][65];
    int bid = blockIdx.x, t = threadIdx.x;
    if (bid < 32) {
        int m = bid >> 4, tl = bid & 15, ti = tl >> 2, tj = tl & 3;
        const float* W = m ? p.Wn2 : p.Wn1;
        float* WT = m ? p.WnT2 : p.WnT1;
#pragma unroll
        for (int k = 0; k < 16; ++k) {
            int idx = k * 256 + t, r = idx >> 6, c = idx & 63;
            tile[r][c] = W[(ti * 64 + r) * CC + tj * 64 + c];
        }
        __syncthreads();
#pragma unroll
        for (int k = 0; k < 16; ++k) {
            int idx = k * 256 + t, r = idx >> 6, c = idx & 63;
            WT[(tj * 64 + r) * CC + ti * 64 + c] = tile[c][r];
        }
    } else if (bid < 40) {
        int idx = (bid - 32) * 256 + t;
        int l = idx >> 10, h = (idx >> 8) & 3, c = idx & 255;
        const float* We = l ? p.We2 : p.We1;
        const float* ae = l ? p.ae2 : p.ae1;
        float s = 0.f;
        for (int d = 0; d < DD; ++d) s += We[(h * DD + d) * CC + c];
        p.wsum[(l * HH + h) * CC + c] = s * ae[h];
    } else {
        p.cnt[(bid - 40) * 256 + t] = 0;
    }
}

// ---------------- K2: pe (first, 16 edges/wave, NT ef loads) || fill || proj1 ----------------
// bid 0..511: pe (64 edges/block) ; 512..639: fill ; 640..1151: proj1
__global__ __launch_bounds__(NTHR) void k_main1(Params p) {
    int bid = blockIdx.x, t = threadIdx.x;
    if (bid < 512) {
        int pb = bid, wid = t >> 6, lane = t & 63;
        float4 wv[8];
#pragma unroll
        for (int i = 0; i < 8; ++i)
            wv[i] = *(const float4*)(p.wsum + i * CC + lane * 4);
        int e0 = pb * 64 + wid * 16;
        int se[16], ge[16];
#pragma unroll
        for (int q = 0; q < 4; ++q) {
            int4 s4 = *(const int4*)(p.src + e0 + q * 4);
            int4 g4 = *(const int4*)(p.trg + e0 + q * 4);
            se[q * 4 + 0] = s4.x; se[q * 4 + 1] = s4.y;
            se[q * 4 + 2] = s4.z; se[q * 4 + 3] = s4.w;
            ge[q * 4 + 0] = g4.x; ge[q * 4 + 1] = g4.y;
            ge[q * 4 + 2] = g4.z; ge[q * 4 + 3] = g4.w;
        }
        // ef rows are read exactly once across the whole workload -> nontemporal
        // (native ext_vector type: __builtin_nontemporal_load rejects HIP float4).
        floatx4 v[16];
#pragma unroll
        for (int k = 0; k < 16; ++k)
            v[k] = __builtin_nontemporal_load(
                (const floatx4*)(p.ef + ((long)se[k] * NN + ge[k]) * CC + lane * 4));
#pragma unroll
        for (int k = 0; k < 16; ++k) {
            float acc[8];
#pragma unroll
            for (int i = 0; i < 8; ++i)
                acc[i] = v[k][0] * wv[i].x + v[k][1] * wv[i].y + v[k][2] * wv[i].z
                       + v[k][3] * wv[i].w;
#pragma unroll
            for (int off = 32; off; off >>= 1)
#pragma unroll
                for (int i = 0; i < 8; ++i) acc[i] += __shfl_down(acc[i], off, 64);
            if (lane == 0) {
                int e = e0 + k;
                *(float4*)(p.pe + (size_t)e * HH) =
                    make_float4(acc[0], acc[1], acc[2], acc[3]);
                *(float4*)(p.pe + (size_t)EE * HH + (size_t)e * HH) =
                    make_float4(acc[4], acc[5], acc[6], acc[7]);
            }
        }
    } else if (bid < 640) {
        int e = (bid - 512) * NTHR + t;
        int n = p.trg[e];
        int pos = atomicAdd(&p.cnt[n], 1);
        if (pos < CAP) p.bucket[n * CAP + pos] = e;
    } else {
        proj_body(p.x, p.WnT1, p.as1, p.at1, p.hbuf, p.alphas, p.alphat, bid - 640, t);
    }
}

// ---------------- K3: fused agg1 + proj2 ; block = node, wave = batch ----------------
__global__ __launch_bounds__(NTHR) void k_fuse1(Params p) {
    __shared__ int sedge[CAP];
    __shared__ int ssrc[CAP];
    __shared__ float spe[CAP][HH];
    __shared__ float sex[CAP][16];
    __shared__ float salt[16];
    __shared__ float x1s[4][CC];
    __shared__ int sdeg;
    int n = blockIdx.x, t = threadIdx.x, b = t >> 6, lane = t & 63;
    int deg = p.cnt[n];
    if (deg > CAP) deg = CAP;
    if (b == 0) {
        if (lane == 0) sdeg = deg;
        sort_bucket(p, n, deg, lane, sedge);
    }
    if (t < 16) salt[t] = p.alphat[(size_t)n * 16 + t];
    __syncthreads();
    if (t < deg) {
        int e = sedge[t];
        int s = p.src[e];
        ssrc[t] = s;
        *(float4*)spe[t] = *(const float4*)(p.pe + (size_t)e * HH);
        p.sedge_g[n * CAP + t] = e;
        p.ssrc_g[n * CAP + t] = s;
    }
    __syncthreads();
    score_exp(p.alphas, salt, t, deg, ssrc, spe, sex);
    __syncthreads();

    // agg layer 1 -> x1 row (node n, batch b) in LDS
    int h = lane >> 4, bh = b * 4 + h;
    float ax = 0.f, ay = 0.f, az = 0.f, aw = 0.f, den = 0.f;
#pragma unroll 8
    for (int i = 0; i < deg; ++i) {
        float ex = sex[i][bh];
        float4 v = *(const float4*)(p.hbuf + ((size_t)ssrc[i] * BB + b) * CC + lane * 4);
        ax += ex * v.x; ay += ex * v.y; az += ex * v.z; aw += ex * v.w;
        den += ex;
    }
    float inv = 1.f / (den + 1e-16f);
    *(float4*)&x1s[b][lane * 4] = make_float4(ax * inv, ay * inv, az * inv, aw * inv);
    __syncthreads();

    // proj2 on the 4 LDS rows of this node
    float acc[4];
#pragma unroll
    for (int r = 0; r < 4; ++r) acc[r] = 0.f;
#pragma unroll 4
    for (int c = 0; c < CC; ++c) {
        float w = p.WnT2[c * CC + t];
#pragma unroll
        for (int r = 0; r < 4; ++r) acc[r] += w * x1s[r][c];
    }
    int hh = t >> 6, d = t & 63;
    float as = p.as2[hh * DD + d], at = p.at2[hh * DD + d];
#pragma unroll
    for (int r = 0; r < 4; ++r) {
        p.hbuf2[((size_t)n * BB + r) * CC + t] = acc[r];
        float vs = acc[r] * as, vt = acc[r] * at;
#pragma unroll
        for (int off = 32; off; off >>= 1) {
            vs += __shfl_down(vs, off, 64);
            vt += __shfl_down(vt, off, 64);
        }
        if (d == 0) {
            p.alphas2[(size_t)n * 16 + r * 4 + hh] = vs;
            p.alphat2[(size_t)n * 16 + r * 4 + hh] = vt;
        }
    }
}

// ---------------- K4: agg layer 2 ; block = node, wave = batch (sorted list reused) ----------------
__global__ __launch_bounds__(NTHR) void k_agg2(Params p) {
    __shared__ int ssrc[CAP];
    __shared__ float spe[CAP][HH];
    __shared__ float sex[CAP][16];
    __shared__ float salt[16];
    int n = blockIdx.x, t = threadIdx.x, b = t >> 6, lane = t & 63;
    int deg = p.cnt[n];
    if (deg > CAP) deg = CAP;
    if (t < 16) salt[t] = p.alphat2[(size_t)n * 16 + t];
    if (t < deg) {
        int e = p.sedge_g[n * CAP + t];
        ssrc[t] = p.ssrc_g[n * CAP + t];
        *(float4*)spe[t] = *(const float4*)(p.pe + (size_t)EE * HH + (size_t)e * HH);
    }
    __syncthreads();
    score_exp(p.alphas2, salt, t, deg, ssrc, spe, sex);
    __syncthreads();

    int h = lane >> 4, bh = b * 4 + h;
    float ax = 0.f, ay = 0.f, az = 0.f, aw = 0.f, den = 0.f;
#pragma unroll 8
    for (int i = 0; i < deg; ++i) {
        float ex = sex[i][bh];
        float4 v = *(const float4*)(p.hbuf2 + ((size_t)ssrc[i] * BB + b) * CC + lane * 4);
        ax += ex * v.x; ay += ex * v.y; az += ex * v.z; aw += ex * v.w;
        den += ex;
    }
    float inv = 1.f / (den + 1e-16f);
    *(float4*)(p.out + ((size_t)n * BB + b) * CC + lane * 4) =
        make_float4(ax * inv, ay * inv, az * inv, aw * inv);
}

// ---------------- launch ----------------
extern "C" void kernel_launch(void* const* d_in, const int* in_sizes, int n_in,
                              void* d_out, int out_size, void* d_ws, size_t ws_size,
                              hipStream_t stream) {
    float* wsf = (float*)d_ws;
    Params p;
    p.x   = (const float*)d_in[0];
    p.ef  = (const float*)d_in[1];
    p.src = (const int*)d_in[2];
    p.trg = (const int*)d_in[3];
    p.Wn1 = (const float*)d_in[4];
    p.We1 = (const float*)d_in[5];
    p.as1 = (const float*)d_in[6];
    p.at1 = (const float*)d_in[7];
    p.ae1 = (const float*)d_in[8];
    p.Wn2 = (const float*)d_in[9];
    p.We2 = (const float*)d_in[10];
    p.as2 = (const float*)d_in[11];
    p.at2 = (const float*)d_in[12];
    p.ae2 = (const float*)d_in[13];
    p.out = (float*)d_out;
    p.WnT1    = wsf;                  // 65536
    p.WnT2    = wsf + 65536;          // 65536
    p.wsum    = wsf + 131072;         // 2048
    p.pe      = wsf + 133120;         // 262144
    p.hbuf    = wsf + 395264;         // 1048576
    p.alphas  = wsf + 1443840;        // 16384
    p.alphat  = wsf + 1460224;        // 16384
    p.hbuf2   = wsf + 1476608;        // 1048576
    p.alphas2 = wsf + 2525184;        // 16384
    p.alphat2 = wsf + 2541568;        // 16384
    p.cnt     = (int*)(wsf + 2557952);                    // 1024
    p.bucket  = (int*)(wsf + 2557952 + 1024);             // 1024*128
    p.sedge_g = (int*)(wsf + 2557952 + 1024 + NN * CAP);  // 1024*128
    p.ssrc_g  = (int*)(wsf + 2557952 + 1024 + 2 * NN * CAP);

    k_prep<<<44, NTHR, 0, stream>>>(p);
    k_main1<<<1152, NTHR, 0, stream>>>(p);
    k_fuse1<<<NN, NTHR, 0, stream>>>(p);
    k_agg2<<<NN, NTHR, 0, stream>>>(p);
}

// Round 20
// 86.837 us; speedup vs baseline: 1.0915x; 1.0915x over previous
//
#include <hip/hip_runtime.h>
#include <cstdint>
#include <cstddef>

#define NN 1024
#define BB 4
#define CC 256
#define HH 4
#define DD 64
#define EE 32768
#define ROWS 8
#define CAP 128
#define NTHR 256

struct Params {
    const float *x, *ef;
    const int *src, *trg;
    const float *Wn1, *We1, *as1, *at1, *ae1;
    const float *Wn2, *We2, *as2, *at2, *ae2;
    float *out;
    float *WnT1, *WnT2, *wsum, *pe, *hbuf, *alphas, *alphat;
    float *hbuf2, *alphas2, *alphat2;
    int *cnt, *bucket, *sedge_g, *ssrc_g;
};

// ---------------- proj: rows r0..r0+7 of (x @ Wn.T); x via wave-uniform scalar loads ----------------
__device__ __forceinline__ void proj_body(const float* __restrict__ x,
                                          const float* __restrict__ WT,
                                          const float* __restrict__ a_s,
                                          const float* __restrict__ a_t,
                                          float* __restrict__ hout,
                                          float* __restrict__ alpha_s,
                                          float* __restrict__ alpha_t,
                                          int bid, int t) {
    int r0 = bid * ROWS;
    const float* xr = x + (size_t)r0 * CC;
    float acc[ROWS];
#pragma unroll
    for (int j = 0; j < ROWS; ++j) acc[j] = 0.f;
#pragma unroll 4
    for (int c = 0; c < CC; ++c) {
        float w = WT[c * CC + t];
#pragma unroll
        for (int j = 0; j < ROWS; ++j) acc[j] += w * xr[(size_t)j * CC + c];
    }
    int h = t >> 6, d = t & 63;
    float as = a_s[h * DD + d], at = a_t[h * DD + d];
#pragma unroll
    for (int j = 0; j < ROWS; ++j) {
        hout[(size_t)(r0 + j) * CC + t] = acc[j];
        float vs = acc[j] * as, vt = acc[j] * at;
#pragma unroll
        for (int off = 32; off; off >>= 1) {
            vs += __shfl_down(vs, off, 64);
            vt += __shfl_down(vt, off, 64);
        }
        if (d == 0) {
            alpha_s[(size_t)(r0 + j) * HH + h] = vs;
            alpha_t[(size_t)(r0 + j) * HH + h] = vt;
        }
    }
}

// rank-sort node n's bucket (deg<=64 wave-parallel; else serial) into sed[]
__device__ __forceinline__ void sort_bucket(const Params& p, int n, int deg, int lane,
                                            int* sed) {
    if (deg <= 64) {
        int v = (lane < deg) ? p.bucket[n * CAP + lane] : 0x7fffffff;
        int rank = 0;
#pragma unroll
        for (int j = 0; j < 64; ++j) {
            int vj = __shfl(v, j, 64);
            rank += (vj < v) ? 1 : 0;
        }
        if (lane < deg) sed[rank] = v;
    } else if (lane == 0) {
        for (int i = 0; i < deg; ++i) sed[i] = p.bucket[n * CAP + i];
        for (int i = 1; i < deg; ++i) {
            int v = sed[i], j = i - 1;
            while (j >= 0 && sed[j] > v) { sed[j + 1] = sed[j]; --j; }
            sed[j + 1] = v;
        }
    }
}

// cooperative score+exp precompute: sex[i][b*4+h] for all deg*16 pairs
__device__ __forceinline__ void score_exp(const float* __restrict__ als,
                                          const float* salt, int t, int deg,
                                          const int* ssrc, const float (*spe)[HH],
                                          float (*sex)[16]) {
#pragma unroll
    for (int k = 0; k < 8; ++k) {
        int idx = k * NTHR + t;
        if (idx < deg * 16) {
            int i = idx >> 4, bh = idx & 15;
            int s = ssrc[i];
            float sc = als[(size_t)s * 16 + bh] + salt[bh] + spe[i][bh & 3];
            sc = sc > 0.f ? sc : 0.2f * sc;
            sex[i][bh] = __expf(sc);
        }
    }
}

// ---------------- K1: transposes + wsum + cnt zero ----------------
__global__ __launch_bounds__(NTHR) void k_prep(Params p) {
    __shared__ float tile[64][65];
    int bid = blockIdx.x, t = threadIdx.x;
    if (bid < 32) {
        int m = bid >> 4, tl = bid & 15, ti = tl >> 2, tj = tl & 3;
        const float* W = m ? p.Wn2 : p.Wn1;
        float* WT = m ? p.WnT2 : p.WnT1;
#pragma unroll
        for (int k = 0; k < 16; ++k) {
            int idx = k * 256 + t, r = idx >> 6, c = idx & 63;
            tile[r][c] = W[(ti * 64 + r) * CC + tj * 64 + c];
        }
        __syncthreads();
#pragma unroll
        for (int k = 0; k < 16; ++k) {
            int idx = k * 256 + t, r = idx >> 6, c = idx & 63;
            WT[(tj * 64 + r) * CC + ti * 64 + c] = tile[c][r];
        }
    } else if (bid < 40) {
        int idx = (bid - 32) * 256 + t;
        int l = idx >> 10, h = (idx >> 8) & 3, c = idx & 255;
        const float* We = l ? p.We2 : p.We1;
        const float* ae = l ? p.ae2 : p.ae1;
        float s = 0.f;
        for (int d = 0; d < DD; ++d) s += We[(h * DD + d) * CC + c];
        p.wsum[(l * HH + h) * CC + c] = s * ae[h];
    } else {
        p.cnt[(bid - 40) * 256 + t] = 0;
    }
}

// ---------------- K2: pe (first, 16 edges/wave) || fill || proj1 ----------------
// bid 0..511: pe (64 edges/block) ; 512..639: fill ; 640..1151: proj1
__global__ __launch_bounds__(NTHR) void k_main1(Params p) {
    int bid = blockIdx.x, t = threadIdx.x;
    if (bid < 512) {
        int pb = bid, wid = t >> 6, lane = t & 63;
        float4 wv[8];
#pragma unroll
        for (int i = 0; i < 8; ++i)
            wv[i] = *(const float4*)(p.wsum + i * CC + lane * 4);
        int e0 = pb * 64 + wid * 16;
        int se[16], ge[16];
#pragma unroll
        for (int q = 0; q < 4; ++q) {
            int4 s4 = *(const int4*)(p.src + e0 + q * 4);
            int4 g4 = *(const int4*)(p.trg + e0 + q * 4);
            se[q * 4 + 0] = s4.x; se[q * 4 + 1] = s4.y;
            se[q * 4 + 2] = s4.z; se[q * 4 + 3] = s4.w;
            ge[q * 4 + 0] = g4.x; ge[q * 4 + 1] = g4.y;
            ge[q * 4 + 2] = g4.z; ge[q * 4 + 3] = g4.w;
        }
        float4 v[16];
#pragma unroll
        for (int k = 0; k < 16; ++k)
            v[k] = *(const float4*)(p.ef + ((long)se[k] * NN + ge[k]) * CC + lane * 4);
#pragma unroll
        for (int k = 0; k < 16; ++k) {
            float acc[8];
#pragma unroll
            for (int i = 0; i < 8; ++i)
                acc[i] = v[k].x * wv[i].x + v[k].y * wv[i].y + v[k].z * wv[i].z
                       + v[k].w * wv[i].w;
#pragma unroll
            for (int off = 32; off; off >>= 1)
#pragma unroll
                for (int i = 0; i < 8; ++i) acc[i] += __shfl_down(acc[i], off, 64);
            if (lane == 0) {
                int e = e0 + k;
                *(float4*)(p.pe + (size_t)e * HH) =
                    make_float4(acc[0], acc[1], acc[2], acc[3]);
                *(float4*)(p.pe + (size_t)EE * HH + (size_t)e * HH) =
                    make_float4(acc[4], acc[5], acc[6], acc[7]);
            }
        }
    } else if (bid < 640) {
        int e = (bid - 512) * NTHR + t;
        int n = p.trg[e];
        int pos = atomicAdd(&p.cnt[n], 1);
        if (pos < CAP) p.bucket[n * CAP + pos] = e;
    } else {
        proj_body(p.x, p.WnT1, p.as1, p.at1, p.hbuf, p.alphas, p.alphat, bid - 640, t);
    }
}

// ---------------- K3: fused agg1 + proj2 ; block = node, wave = batch ----------------
__global__ __launch_bounds__(NTHR) void k_fuse1(Params p) {
    __shared__ int sedge[CAP];
    __shared__ int ssrc[CAP];
    __shared__ float spe[CAP][HH];
    __shared__ float sex[CAP][16];
    __shared__ float salt[16];
    __shared__ float x1s[4][CC];
    __shared__ int sdeg;
    int n = blockIdx.x, t = threadIdx.x, b = t >> 6, lane = t & 63;
    int deg = p.cnt[n];
    if (deg > CAP) deg = CAP;
    if (b == 0) {
        if (lane == 0) sdeg = deg;
        sort_bucket(p, n, deg, lane, sedge);
    }
    if (t < 16) salt[t] = p.alphat[(size_t)n * 16 + t];
    __syncthreads();
    if (t < deg) {
        int e = sedge[t];
        int s = p.src[e];
        ssrc[t] = s;
        *(float4*)spe[t] = *(const float4*)(p.pe + (size_t)e * HH);
        p.sedge_g[n * CAP + t] = e;
        p.ssrc_g[n * CAP + t] = s;
    }
    __syncthreads();
    score_exp(p.alphas, salt, t, deg, ssrc, spe, sex);
    __syncthreads();

    // agg layer 1 -> x1 row (node n, batch b) in LDS
    int h = lane >> 4, bh = b * 4 + h;
    float ax = 0.f, ay = 0.f, az = 0.f, aw = 0.f, den = 0.f;
#pragma unroll 8
    for (int i = 0; i < deg; ++i) {
        float ex = sex[i][bh];
        float4 v = *(const float4*)(p.hbuf + ((size_t)ssrc[i] * BB + b) * CC + lane * 4);
        ax += ex * v.x; ay += ex * v.y; az += ex * v.z; aw += ex * v.w;
        den += ex;
    }
    float inv = 1.f / (den + 1e-16f);
    *(float4*)&x1s[b][lane * 4] = make_float4(ax * inv, ay * inv, az * inv, aw * inv);
    __syncthreads();

    // proj2 on the 4 LDS rows of this node
    float acc[4];
#pragma unroll
    for (int r = 0; r < 4; ++r) acc[r] = 0.f;
#pragma unroll 4
    for (int c = 0; c < CC; ++c) {
        float w = p.WnT2[c * CC + t];
#pragma unroll
        for (int r = 0; r < 4; ++r) acc[r] += w * x1s[r][c];
    }
    int hh = t >> 6, d = t & 63;
    float as = p.as2[hh * DD + d], at = p.at2[hh * DD + d];
#pragma unroll
    for (int r = 0; r < 4; ++r) {
        p.hbuf2[((size_t)n * BB + r) * CC + t] = acc[r];
        float vs = acc[r] * as, vt = acc[r] * at;
#pragma unroll
        for (int off = 32; off; off >>= 1) {
            vs += __shfl_down(vs, off, 64);
            vt += __shfl_down(vt, off, 64);
        }
        if (d == 0) {
            p.alphas2[(size_t)n * 16 + r * 4 + hh] = vs;
            p.alphat2[(size_t)n * 16 + r * 4 + hh] = vt;
        }
    }
}

// ---------------- K4: agg layer 2 ; block = node, wave = batch (sorted list reused) ----------------
__global__ __launch_bounds__(NTHR) void k_agg2(Params p) {
    __shared__ int ssrc[CAP];
    __shared__ float spe[CAP][HH];
    __shared__ float sex[CAP][16];
    __shared__ float salt[16];
    int n = blockIdx.x, t = threadIdx.x, b = t >> 6, lane = t & 63;
    int deg = p.cnt[n];
    if (deg > CAP) deg = CAP;
    if (t < 16) salt[t] = p.alphat2[(size_t)n * 16 + t];
    if (t < deg) {
        int e = p.sedge_g[n * CAP + t];
        ssrc[t] = p.ssrc_g[n * CAP + t];
        *(float4*)spe[t] = *(const float4*)(p.pe + (size_t)EE * HH + (size_t)e * HH);
    }
    __syncthreads();
    score_exp(p.alphas2, salt, t, deg, ssrc, spe, sex);
    __syncthreads();

    int h = lane >> 4, bh = b * 4 + h;
    float ax = 0.f, ay = 0.f, az = 0.f, aw = 0.f, den = 0.f;
#pragma unroll 8
    for (int i = 0; i < deg; ++i) {
        float ex = sex[i][bh];
        float4 v = *(const float4*)(p.hbuf2 + ((size_t)ssrc[i] * BB + b) * CC + lane * 4);
        ax += ex * v.x; ay += ex * v.y; az += ex * v.z; aw += ex * v.w;
        den += ex;
    }
    float inv = 1.f / (den + 1e-16f);
    *(float4*)(p.out + ((size_t)n * BB + b) * CC + lane * 4) =
        make_float4(ax * inv, ay * inv, az * inv, aw * inv);
}

// ---------------- launch ----------------
extern "C" void kernel_launch(void* const* d_in, const int* in_sizes, int n_in,
                              void* d_out, int out_size, void* d_ws, size_t ws_size,
                              hipStream_t stream) {
    float* wsf = (float*)d_ws;
    Params p;
    p.x   = (const float*)d_in[0];
    p.ef  = (const float*)d_in[1];
    p.src = (const int*)d_in[2];
    p.trg = (const int*)d_in[3];
    p.Wn1 = (const float*)d_in[4];
    p.We1 = (const float*)d_in[5];
    p.as1 = (const float*)d_in[6];
    p.at1 = (const float*)d_in[7];
    p.ae1 = (const float*)d_in[8];
    p.Wn2 = (const float*)d_in[9];
    p.We2 = (const float*)d_in[10];
    p.as2 = (const float*)d_in[11];
    p.at2 = (const float*)d_in[12];
    p.ae2 = (const float*)d_in[13];
    p.out = (float*)d_out;
    p.WnT1    = wsf;                  // 65536
    p.WnT2    = wsf + 65536;          // 65536
    p.wsum    = wsf + 131072;         // 2048
    p.pe      = wsf + 133120;         // 262144
    p.hbuf    = wsf + 395264;         // 1048576
    p.alphas  = wsf + 1443840;        // 16384
    p.alphat  = wsf + 1460224;        // 16384
    p.hbuf2   = wsf + 1476608;        // 1048576
    p.alphas2 = wsf + 2525184;        // 16384
    p.alphat2 = wsf + 2541568;        // 16384
    p.cnt     = (int*)(wsf + 2557952);                    // 1024
    p.bucket  = (int*)(wsf + 2557952 + 1024);             // 1024*128
    p.sedge_g = (int*)(wsf + 2557952 + 1024 + NN * CAP);  // 1024*128
    p.ssrc_g  = (int*)(wsf + 2557952 + 1024 + 2 * NN * CAP);

    k_prep<<<44, NTHR, 0, stream>>>(p);
    k_main1<<<1152, NTHR, 0, stream>>>(p);
    k_fuse1<<<NN, NTHR, 0, stream>>>(p);
    k_agg2<<<NN, NTHR, 0, stream>>>(p);
}